// Round 1
// baseline (887.870 us; speedup 1.0000x reference)
//
#include <hip/hip_runtime.h>
#include <float.h>
#include <math.h>

#define NN 4096
#define FF 512
#define KK 8
#define DD 64

// -------------------- Kernel 1: HW[k] = H @ W_k  (fp32 tiled GEMM) ----------
__global__ __launch_bounds__(256) void k_hw(const float* __restrict__ H,
                                            const float* __restrict__ Wk,
                                            float* __restrict__ HW) {
  __shared__ __align__(16) float Ht[64][68];
  __shared__ __align__(16) float Wt[64][68];
  const int i0 = blockIdx.x * 64;
  const int k  = blockIdx.y;
  const int tid = threadIdx.x;
  const int lane = tid & 63, wave = tid >> 6;
  const int tx = tid & 15, ty = tid >> 4;
  float acc[4][4] = {};
  for (int f0 = 0; f0 < FF; f0 += 64) {
    #pragma unroll
    for (int e = 0; e < 16; ++e) {
      int r = e * 4 + wave;
      Ht[r][lane] = H[(size_t)(i0 + r) * FF + f0 + lane];
      Wt[r][lane] = Wk[(size_t)k * FF * DD + (size_t)(f0 + r) * DD + lane];
    }
    __syncthreads();
    #pragma unroll 8
    for (int ff = 0; ff < 64; ++ff) {
      float4 b = *reinterpret_cast<const float4*>(&Wt[ff][tx * 4]);
      #pragma unroll
      for (int i = 0; i < 4; ++i) {
        float a = Ht[ty * 4 + i][ff];
        acc[i][0] += a * b.x; acc[i][1] += a * b.y;
        acc[i][2] += a * b.z; acc[i][3] += a * b.w;
      }
    }
    __syncthreads();
  }
  #pragma unroll
  for (int i = 0; i < 4; ++i)
    #pragma unroll
    for (int d = 0; d < 4; ++d)
      HW[((size_t)k * NN + i0 + ty * 4 + i) * DD + tx * 4 + d] = acc[i][d];
}

// -------------------- Kernel 2: s1[k,n], s2[k,n] ----------------------------
__global__ __launch_bounds__(256) void k_s12(const float* __restrict__ HW,
                                             const float* __restrict__ attk,
                                             float* __restrict__ s1,
                                             float* __restrict__ s2) {
  const int w = blockIdx.x * 4 + (threadIdx.x >> 6);   // global wave id = k*N+n
  const int lane = threadIdx.x & 63;
  const int k = w >> 12;          // / 4096
  const int n = w & 4095;
  float hv = HW[((size_t)k * NN + n) * DD + lane];
  float v1 = hv * attk[k * 2 * DD + lane];
  float v2 = hv * attk[k * 2 * DD + DD + lane];
  #pragma unroll
  for (int off = 32; off; off >>= 1) {
    v1 += __shfl_down(v1, off);
    v2 += __shfl_down(v2, off);
  }
  if (lane == 0) { s1[k * NN + n] = v1; s2[k * NN + n] = v2; }
}

// -------------------- Kernel 3: per-row max m and 1/sum(exp) ----------------
__global__ __launch_bounds__(256) void k_ml(const float* __restrict__ A,
                                            const float* __restrict__ s1,
                                            const float* __restrict__ s2,
                                            float* __restrict__ mrow,
                                            float* __restrict__ rinv) {
  const int i = blockIdx.x;
  const int tid = threadIdx.x;
  float s1k[KK];
  #pragma unroll
  for (int k = 0; k < KK; ++k) s1k[k] = s1[k * NN + i];
  float m[KK], l[KK];
  #pragma unroll
  for (int k = 0; k < KK; ++k) { m[k] = -FLT_MAX; l[k] = 0.f; }
  const float* Arow = A + (size_t)i * NN;
  for (int it = 0; it < NN / 256; ++it) {
    int j = it * 256 + tid;
    float a = Arow[j];
    if (a != 0.f) {
      #pragma unroll
      for (int k = 0; k < KK; ++k) {
        float sc = s1k[k] + s2[k * NN + j];
        sc = fmaxf(sc, 0.2f * sc);               // leaky relu
        if (sc > m[k]) {
          l[k] = l[k] * __expf(m[k] - sc) + 1.f;
          m[k] = sc;
        } else {
          l[k] += __expf(sc - m[k]);
        }
      }
    }
  }
  // wave reduce
  #pragma unroll
  for (int k = 0; k < KK; ++k) {
    for (int off = 32; off; off >>= 1) {
      float mo = __shfl_xor(m[k], off);
      float lo = __shfl_xor(l[k], off);
      float mn = fmaxf(m[k], mo);
      l[k] = l[k] * __expf(m[k] - mn) + lo * __expf(mo - mn);
      m[k] = mn;
    }
  }
  __shared__ float pm[4][KK], pl[4][KK];
  const int wave = tid >> 6, lane = tid & 63;
  if (lane == 0) {
    #pragma unroll
    for (int k = 0; k < KK; ++k) { pm[wave][k] = m[k]; pl[wave][k] = l[k]; }
  }
  __syncthreads();
  if (tid < KK) {
    float mm = -FLT_MAX, ll = 0.f;
    #pragma unroll
    for (int w = 0; w < 4; ++w) {
      float mo = pm[w][tid], lo = pl[w][tid];
      float mn = fmaxf(mm, mo);
      ll = ll * __expf(mm - mn) + lo * __expf(mo - mn);
      mm = mn;
    }
    mrow[tid * NN + i] = mm;
    rinv[tid * NN + i] = 1.0f / ll;
  }
}

// -------------------- Kernel 4: out = elu(P @ HW + bias) --------------------
__global__ __launch_bounds__(256) void k_attn(const float* __restrict__ A,
                                              const float* __restrict__ HW,
                                              const float* __restrict__ s1,
                                              const float* __restrict__ s2,
                                              const float* __restrict__ mrow,
                                              const float* __restrict__ rinv,
                                              const float* __restrict__ bias,
                                              float* __restrict__ out) {
  __shared__ __align__(16) float P[64][68];
  __shared__ __align__(16) float HWt[64][68];
  const int i0 = blockIdx.x * 64;
  const int k  = blockIdx.y;
  const int tid = threadIdx.x;
  const int lane = tid & 63, wave = tid >> 6;
  const int tx = tid & 15, ty = tid >> 4;
  const float* s2k = s2 + (size_t)k * NN;
  float acc[4][4] = {};
  for (int j0 = 0; j0 < NN; j0 += 64) {
    #pragma unroll
    for (int e = 0; e < 16; ++e) {
      int r = e * 4 + wave;               // uniform within wave
      float a = A[(size_t)(i0 + r) * NN + j0 + lane];
      float p = 0.f;
      if (a != 0.f) {
        float sc = s1[k * NN + i0 + r] + s2k[j0 + lane];
        sc = fmaxf(sc, 0.2f * sc);
        p = __expf(sc - mrow[k * NN + i0 + r]) * rinv[k * NN + i0 + r];
      }
      P[r][lane] = p;
      HWt[r][lane] = HW[((size_t)k * NN + j0 + r) * DD + lane];
    }
    __syncthreads();
    #pragma unroll 8
    for (int jj = 0; jj < 64; ++jj) {
      float4 hv = *reinterpret_cast<const float4*>(&HWt[jj][tx * 4]);
      #pragma unroll
      for (int i = 0; i < 4; ++i) {
        float p = P[ty * 4 + i][jj];
        acc[i][0] += p * hv.x; acc[i][1] += p * hv.y;
        acc[i][2] += p * hv.z; acc[i][3] += p * hv.w;
      }
    }
    __syncthreads();
  }
  #pragma unroll
  for (int i = 0; i < 4; ++i) {
    int row = i0 + ty * 4 + i;
    #pragma unroll
    for (int d = 0; d < 4; ++d) {
      float v = acc[i][d] + bias[k * DD + tx * 4 + d];
      v = v > 0.f ? v : expm1f(v);       // ELU
      out[(size_t)row * (KK * DD) + k * DD + tx * 4 + d] = v;
    }
  }
}

// ---------------------------------------------------------------------------
extern "C" void kernel_launch(void* const* d_in, const int* in_sizes, int n_in,
                              void* d_out, int out_size, void* d_ws, size_t ws_size,
                              hipStream_t stream) {
  const float* H    = (const float*)d_in[0];
  const float* A    = (const float*)d_in[1];
  // d_in[2] = idx = arange(N) -> identity gather, ignored
  const float* Wk   = (const float*)d_in[3];
  const float* attk = (const float*)d_in[4];
  const float* bias = (const float*)d_in[5];
  float* out = (float*)d_out;

  float* ws   = (float*)d_ws;
  float* HWp  = ws;                       // K*N*D = 2097152 floats
  float* s1p  = ws + (size_t)KK * NN * DD;
  float* s2p  = s1p + KK * NN;
  float* mp   = s2p + KK * NN;
  float* rp   = mp + KK * NN;

  k_hw<<<dim3(NN / 64, KK), 256, 0, stream>>>(H, Wk, HWp);
  k_s12<<<KK * NN / 4, 256, 0, stream>>>(HWp, attk, s1p, s2p);
  k_ml<<<NN, 256, 0, stream>>>(A, s1p, s2p, mp, rp);
  k_attn<<<dim3(NN / 64, KK), 256, 0, stream>>>(A, HWp, s1p, s2p, mp, rp, bias, out);
}

// Round 2
// 262.069 us; speedup vs baseline: 3.3879x; 3.3879x over previous
//
#include <hip/hip_runtime.h>
#include <hip/hip_fp16.h>
#include <float.h>
#include <math.h>

#define NN 4096
#define FF 512
#define KK 8
#define DD 64

typedef float f32x4 __attribute__((ext_vector_type(4)));
typedef _Float16 f16x4 __attribute__((ext_vector_type(4)));
typedef _Float16 f16x8 __attribute__((ext_vector_type(8)));

// ---------------- K1: adjacency -> bitmask (1 bit per edge) -----------------
__global__ __launch_bounds__(256) void k_bits(const float* __restrict__ A,
                                              unsigned long long* __restrict__ bits) {
  const int gw   = (blockIdx.x * 256 + threadIdx.x) >> 6;   // global wave id
  const int lane = threadIdx.x & 63;
  const int nw   = (gridDim.x * 256) >> 6;
  const int totw = NN * NN / 64;
  for (int wd = gw; wd < totw; wd += nw) {
    float a = A[(size_t)wd * 64 + lane];
    unsigned long long m = __ballot(a != 0.0f);
    if (lane == 0) bits[wd] = m;
  }
}

// ---------------- K2: HW = H @ W_k (fp32), fused s1/s2 + fp16 HWT -----------
__global__ __launch_bounds__(256) void k_hw(const float* __restrict__ H,
                                            const float* __restrict__ Wk,
                                            const float* __restrict__ attk,
                                            _Float16* __restrict__ HWT,   // [K][D][N]
                                            float* __restrict__ s1,
                                            float* __restrict__ s2) {
  __shared__ __align__(16) float Ht[64][68];
  __shared__ __align__(16) float Wt[64][68];
  const int i0 = blockIdx.x * 64;
  const int k  = blockIdx.y;
  const int tid = threadIdx.x;
  const int lane = tid & 63, wave = tid >> 6;
  const int tx = tid & 15, ty = tid >> 4;
  float acc[4][4] = {};
  for (int f0 = 0; f0 < FF; f0 += 64) {
    #pragma unroll
    for (int e = 0; e < 16; ++e) {
      int r = e * 4 + wave;
      Ht[r][lane] = H[(size_t)(i0 + r) * FF + f0 + lane];
      Wt[r][lane] = Wk[(size_t)k * FF * DD + (size_t)(f0 + r) * DD + lane];
    }
    __syncthreads();
    #pragma unroll 8
    for (int ff = 0; ff < 64; ++ff) {
      float4 b = *reinterpret_cast<const float4*>(&Wt[ff][tx * 4]);
      #pragma unroll
      for (int i = 0; i < 4; ++i) {
        float a = Ht[ty * 4 + i][ff];
        acc[i][0] += a * b.x; acc[i][1] += a * b.y;
        acc[i][2] += a * b.z; acc[i][3] += a * b.w;
      }
    }
    __syncthreads();
  }
  // epilogue 1: fp16 transposed store HWT[k][d][i]
  #pragma unroll
  for (int dd = 0; dd < 4; ++dd) {
    f16x4 hv;
    #pragma unroll
    for (int i = 0; i < 4; ++i) hv[i] = (_Float16)acc[i][dd];
    *reinterpret_cast<f16x4*>(&HWT[((size_t)k * DD + tx * 4 + dd) * NN + i0 + ty * 4]) = hv;
  }
  // epilogue 2: s1/s2 row reductions (reduce over d, i.e. over tx lanes)
  const float* a1 = attk + k * 2 * DD;
  const float* a2 = a1 + DD;
  float p1[4] = {}, p2[4] = {};
  #pragma unroll
  for (int i = 0; i < 4; ++i)
    #pragma unroll
    for (int dd = 0; dd < 4; ++dd) {
      p1[i] += acc[i][dd] * a1[tx * 4 + dd];
      p2[i] += acc[i][dd] * a2[tx * 4 + dd];
    }
  #pragma unroll
  for (int off = 8; off; off >>= 1)
    #pragma unroll
    for (int i = 0; i < 4; ++i) {
      p1[i] += __shfl_xor(p1[i], off);
      p2[i] += __shfl_xor(p2[i], off);
    }
  if (tx == 0) {
    #pragma unroll
    for (int i = 0; i < 4; ++i) {
      s1[k * NN + i0 + ty * 4 + i] = p1[i];
      s2[k * NN + i0 + ty * 4 + i] = p2[i];
    }
  }
}

// ---------------- K3: maxs2[k] = max_j s2[k][j] -----------------------------
__global__ __launch_bounds__(256) void k_mx(const float* __restrict__ s2,
                                            float* __restrict__ mx) {
  const int k = blockIdx.x, tid = threadIdx.x;
  float m = -FLT_MAX;
  for (int j = tid; j < NN; j += 256) m = fmaxf(m, s2[k * NN + j]);
  #pragma unroll
  for (int o = 32; o; o >>= 1) m = fmaxf(m, __shfl_xor(m, o));
  __shared__ float sm[4];
  if ((tid & 63) == 0) sm[tid >> 6] = m;
  __syncthreads();
  if (tid == 0) mx[k] = fmaxf(fmaxf(sm[0], sm[1]), fmaxf(sm[2], sm[3]));
}

// ---------------- K4: out = elu( (Sum_j w*HW) / Sum_j w + bias ) ------------
// w_ij = A_ij * exp(lrelu(s1_i+s2_j) - c_i), c_i = lrelu(s1_i + max s2) >= row max
__global__ __launch_bounds__(256) void k_attn(
    const unsigned long long* __restrict__ bits,
    const _Float16* __restrict__ HWT,
    const float* __restrict__ s1, const float* __restrict__ s2,
    const float* __restrict__ maxs2, const float* __restrict__ bias,
    float* __restrict__ out) {
  __shared__ __align__(16) char Bt[8192];     // fp16 [64 d][64 j], XOR-swizzled
  __shared__ __align__(16) float s2l[NN];     // 16 KB: this head's s2 row
  const int k   = blockIdx.y;
  const int i0  = blockIdx.x * 64;
  const int tid = threadIdx.x;
  const int w = tid >> 6, lane = tid & 63;
  const int grp = lane >> 4, l15 = lane & 15;
  const int row = i0 + w * 16 + l15;          // A-frag row owned by this lane

  for (int t = tid; t < NN / 4; t += 256)
    *reinterpret_cast<float4*>(&s2l[t * 4]) =
        *reinterpret_cast<const float4*>(&s2[k * NN + t * 4]);

  const float s1r = s1[k * NN + row];
  float cr = s1r + maxs2[k];
  cr = fmaxf(cr, 0.2f * cr);
  const unsigned long long* brow = bits + (size_t)row * (NN / 64);
  const _Float16* hwk = HWT + (size_t)k * DD * NN;

  f32x4 acc[4] = {};
  float wsum = 0.f;

  for (int j0 = 0; j0 < NN; j0 += 64) {
    __syncthreads();                          // covers s2l (iter 0) + Bt reuse
    // stage HWT tile [64 d][64 j] -> swizzled LDS (reg-staged, coalesced)
    #pragma unroll
    for (int it = 0; it < 2; ++it) {
      int c = tid + it * 256;
      int d = c >> 3, jc = c & 7;
      float4 v = *reinterpret_cast<const float4*>(hwk + (size_t)d * NN + j0 + jc * 8);
      *reinterpret_cast<float4*>(Bt + ((d * 128 + jc * 16) ^ ((d & 7) << 4))) = v;
    }
    __syncthreads();

    unsigned long long bw = brow[j0 >> 6];
    uint bwlo = (uint)bw, bwhi = (uint)(bw >> 32);

    #pragma unroll
    for (int js = 0; js < 2; ++js) {          // two MFMA k-steps of 32 j
      uint m32 = js ? bwhi : bwlo;
      float4 sA = *reinterpret_cast<const float4*>(&s2l[j0 + js * 32 + grp * 4]);
      float4 sB = *reinterpret_cast<const float4*>(&s2l[j0 + js * 32 + 16 + grp * 4]);
      f16x8 af;
      float wl = 0.f;
      #pragma unroll
      for (int e = 0; e < 4; ++e) {
        float sc = s1r + ((const float*)&sA)[e];
        sc = fmaxf(sc, 0.2f * sc);
        float ex = __expf(sc - cr);
        ex = ((m32 >> (grp * 4 + e)) & 1) ? ex : 0.f;
        wl += ex; af[e] = (_Float16)ex;
        float sc2 = s1r + ((const float*)&sB)[e];
        sc2 = fmaxf(sc2, 0.2f * sc2);
        float ex2 = __expf(sc2 - cr);
        ex2 = ((m32 >> (16 + grp * 4 + e)) & 1) ? ex2 : 0.f;
        wl += ex2; af[4 + e] = (_Float16)ex2;
      }
      wsum += wl;
      #pragma unroll
      for (int n = 0; n < 4; ++n) {
        int b0 = (n * 16 + l15) * 128 + js * 64 + grp * 8;
        int xo = (l15 & 7) << 4;
        f16x4 blo = *reinterpret_cast<const f16x4*>(Bt + (b0 ^ xo));
        f16x4 bhi = *reinterpret_cast<const f16x4*>(Bt + ((b0 + 32) ^ xo));
        f16x8 bf = __builtin_shufflevector(blo, bhi, 0, 1, 2, 3, 4, 5, 6, 7);
        acc[n] = __builtin_amdgcn_mfma_f32_16x16x32_f16(af, bf, acc[n], 0, 0, 0);
      }
    }
  }

  // total w per row (row = l15 lives in lanes l15, l15+16, l15+32, l15+48)
  wsum += __shfl_xor(wsum, 16);
  wsum += __shfl_xor(wsum, 32);

  #pragma unroll
  for (int q = 0; q < 4; ++q) {
    float ws = __shfl(wsum, (lane & 48) | (grp * 4 + q));
    int r = i0 + w * 16 + grp * 4 + q;
    #pragma unroll
    for (int n = 0; n < 4; ++n) {
      float v = acc[n][q] / ws + bias[k * DD + n * 16 + l15];
      v = v > 0.f ? v : expm1f(v);
      out[(size_t)r * (KK * DD) + k * DD + n * 16 + l15] = v;
    }
  }
}

// ---------------------------------------------------------------------------
extern "C" void kernel_launch(void* const* d_in, const int* in_sizes, int n_in,
                              void* d_out, int out_size, void* d_ws, size_t ws_size,
                              hipStream_t stream) {
  const float* H    = (const float*)d_in[0];
  const float* A    = (const float*)d_in[1];
  // d_in[2] = idx = arange(N) -> identity gather, ignored
  const float* Wk   = (const float*)d_in[3];
  const float* attk = (const float*)d_in[4];
  const float* bias = (const float*)d_in[5];
  float* out = (float*)d_out;

  char* base = (char*)d_ws;
  _Float16* HWT = (_Float16*)base;                                   // 4 MB
  unsigned long long* bits = (unsigned long long*)(base + 4u * 1024 * 1024); // 2 MB
  float* s1p = (float*)(base + 6u * 1024 * 1024);                    // 128 KB
  float* s2p = s1p + KK * NN;                                        // 128 KB
  float* mxp = s2p + KK * NN;                                        // 32 B

  k_bits<<<2048, 256, 0, stream>>>(A, bits);
  k_hw<<<dim3(NN / 64, KK), 256, 0, stream>>>(H, Wk, attk, HWT, s1p, s2p);
  k_mx<<<KK, 256, 0, stream>>>(s2p, mxp);
  k_attn<<<dim3(NN / 64, KK), 256, 0, stream>>>(bits, HWT, s1p, s2p, mxp, bias, out);
}

// Round 3
// 197.746 us; speedup vs baseline: 4.4900x; 1.3253x over previous
//
#include <hip/hip_runtime.h>
#include <hip/hip_fp16.h>
#include <float.h>
#include <math.h>

#define NN 4096
#define FF 512
#define KK 8
#define DD 64

typedef float f32x4 __attribute__((ext_vector_type(4)));
typedef _Float16 f16x4 __attribute__((ext_vector_type(4)));
typedef _Float16 f16x8 __attribute__((ext_vector_type(8)));

// ---------------- K1: adjacency -> bitmask (1 bit per edge) -----------------
__global__ __launch_bounds__(256) void k_bits(const float* __restrict__ A,
                                              unsigned long long* __restrict__ bits) {
  const int gw   = (blockIdx.x * 256 + threadIdx.x) >> 6;
  const int lane = threadIdx.x & 63;
  const int nw   = (gridDim.x * 256) >> 6;
  const int totw = NN * NN / 64;
  for (int wd = gw; wd < totw; wd += nw) {
    float a = A[(size_t)wd * 64 + lane];
    unsigned long long m = __ballot(a != 0.0f);
    if (lane == 0) bits[wd] = m;
  }
}

// ---------------- K2: H (fp32) -> HF (fragment-major f16) -------------------
// frag id = rb*16+fb covers rows [rb*16,+16), f [fb*32,+32).
// lane (l15,grp), elem e -> (row=rb*16+l15, f=fb*32+grp*4+(e&3)+16*(e>>2))
__global__ __launch_bounds__(256) void k_hf(const float* __restrict__ H,
                                            _Float16* __restrict__ HF) {
  const int w = threadIdx.x >> 6, lane = threadIdx.x & 63;
  const int tile = blockIdx.x * 4 + w;            // 0..4095
  const int rb = tile >> 4, fb = tile & 15;
  const int l15 = lane & 15, grp = lane >> 4;
  const float* src = H + (size_t)(rb * 16 + l15) * FF + fb * 32 + grp * 4;
  float4 lo = *reinterpret_cast<const float4*>(src);
  float4 hi = *reinterpret_cast<const float4*>(src + 16);
  f16x8 v;
  v[0] = (_Float16)lo.x; v[1] = (_Float16)lo.y; v[2] = (_Float16)lo.z; v[3] = (_Float16)lo.w;
  v[4] = (_Float16)hi.x; v[5] = (_Float16)hi.y; v[6] = (_Float16)hi.z; v[7] = (_Float16)hi.w;
  *reinterpret_cast<f16x8*>(HF + (size_t)tile * 512 + lane * 8) = v;
}

// ---------------- K3: W (fp32 [k][f][d]) -> WF (B-fragment-major f16) -------
// frag id = (k*16+fb)*4+db; lane (l15,grp) e -> (f=fb*32+slot, d=db*16+l15)
__global__ __launch_bounds__(256) void k_wf(const float* __restrict__ Wk,
                                            _Float16* __restrict__ WF) {
  const int g = blockIdx.x * 256 + threadIdx.x;
  const int frag = g >> 6, lane = g & 63;
  const int k = frag >> 6, fb = (frag >> 2) & 15, db = frag & 3;
  const int l15 = lane & 15, grp = lane >> 4;
  f16x8 v;
  #pragma unroll
  for (int e = 0; e < 8; ++e) {
    int f = fb * 32 + grp * 4 + (e & 3) + 16 * (e >> 2);
    int d = db * 16 + l15;
    v[e] = (_Float16)Wk[((size_t)k * FF + f) * DD + d];
  }
  *reinterpret_cast<f16x8*>(WF + (size_t)frag * 512 + lane * 8) = v;
}

// ---------------- K4: HW = H@W (MFMA, no LDS) + s1/s2/e2 + HWF --------------
__global__ __launch_bounds__(256) void k_hw(const _Float16* __restrict__ HF,
                                            const _Float16* __restrict__ WF,
                                            const float* __restrict__ attk,
                                            _Float16* __restrict__ HWF,
                                            float* __restrict__ s1,
                                            float* __restrict__ s2,
                                            float* __restrict__ e2p,
                                            float* __restrict__ e2n) {
  const int w = threadIdx.x >> 6, lane = threadIdx.x & 63;
  const int k = blockIdx.y;
  const int rb = blockIdx.x * 4 + w;              // 16-row block
  const int l15 = lane & 15, grp = lane >> 4;
  f32x4 acc[4] = {};
  for (int fb = 0; fb < 16; ++fb) {
    f16x8 a = *reinterpret_cast<const f16x8*>(HF + (size_t)(rb * 16 + fb) * 512 + lane * 8);
    #pragma unroll
    for (int n = 0; n < 4; ++n) {
      f16x8 b = *reinterpret_cast<const f16x8*>(WF + (size_t)((k * 16 + fb) * 4 + n) * 512 + lane * 8);
      acc[n] = __builtin_amdgcn_mfma_f32_16x16x32_f16(a, b, acc[n], 0, 0, 0);
    }
  }
  // HWF: k_attn B-frag layout. frag=(k*128+jb)*4+db; this wave fills e-half (rb&1).
  const int jb = rb >> 1;
  const int half = rb & 1;
  #pragma unroll
  for (int db = 0; db < 4; ++db) {
    f16x4 v;
    #pragma unroll
    for (int q = 0; q < 4; ++q) v[q] = (_Float16)acc[db][q];
    *reinterpret_cast<f16x4*>(HWF + (size_t)((k * 128 + jb) * 4 + db) * 512 + lane * 8 + half * 4) = v;
  }
  // s1/s2 + exp tables
  float a1v[4], a2v[4];
  #pragma unroll
  for (int n = 0; n < 4; ++n) {
    a1v[n] = attk[k * 2 * DD + n * 16 + l15];
    a2v[n] = attk[k * 2 * DD + DD + n * 16 + l15];
  }
  #pragma unroll
  for (int q = 0; q < 4; ++q) {
    float p1 = 0.f, p2 = 0.f;
    #pragma unroll
    for (int n = 0; n < 4; ++n) { p1 += acc[n][q] * a1v[n]; p2 += acc[n][q] * a2v[n]; }
    #pragma unroll
    for (int off = 8; off; off >>= 1) { p1 += __shfl_xor(p1, off); p2 += __shfl_xor(p2, off); }
    if (l15 == 0) {
      int row = rb * 16 + grp * 4 + q;
      s1[k * NN + row]  = p1;
      s2[k * NN + row]  = p2;
      e2p[k * NN + row] = __expf(p2);
      e2n[k * NN + row] = __expf(0.2f * p2);
    }
  }
}

// ---------------- K5: maxs2[k] ----------------------------------------------
__global__ __launch_bounds__(256) void k_mx(const float* __restrict__ s2,
                                            float* __restrict__ mx) {
  const int k = blockIdx.x, tid = threadIdx.x;
  float m = -FLT_MAX;
  for (int j = tid; j < NN; j += 256) m = fmaxf(m, s2[k * NN + j]);
  #pragma unroll
  for (int o = 32; o; o >>= 1) m = fmaxf(m, __shfl_xor(m, o));
  __shared__ float sm[4];
  if ((tid & 63) == 0) sm[tid >> 6] = m;
  __syncthreads();
  if (tid == 0) mx[k] = fmaxf(fmaxf(sm[0], sm[1]), fmaxf(sm[2], sm[3]));
}

// ---------------- K6: partial attn-PV over a j-half (barrier-free loop) -----
__global__ __launch_bounds__(256, 4) void k_attn(
    const unsigned long long* __restrict__ bits,
    const _Float16* __restrict__ HWF,
    const float* __restrict__ s1, const float* __restrict__ s2,
    const float* __restrict__ e2p, const float* __restrict__ e2n,
    const float* __restrict__ mx,
    float* __restrict__ pacc, float* __restrict__ pw) {
  __shared__ __align__(16) float s2l[2048], epl[2048], enl[2048];
  const int k = blockIdx.y, jh = blockIdx.z;
  const int i0 = blockIdx.x * 64;
  const int tid = threadIdx.x;
  const int w = tid >> 6, lane = tid & 63, l15 = lane & 15, grp = lane >> 4;
  const int jbase = jh * 2048;
  for (int t = tid; t < 512; t += 256) {
    *reinterpret_cast<float4*>(&s2l[t * 4]) = *reinterpret_cast<const float4*>(&s2[k * NN + jbase + t * 4]);
    *reinterpret_cast<float4*>(&epl[t * 4]) = *reinterpret_cast<const float4*>(&e2p[k * NN + jbase + t * 4]);
    *reinterpret_cast<float4*>(&enl[t * 4]) = *reinterpret_cast<const float4*>(&e2n[k * NN + jbase + t * 4]);
  }
  __syncthreads();
  const int row = i0 + w * 16 + l15;
  const float s1r = s1[k * NN + row];
  float cr = s1r + mx[k]; cr = fmaxf(cr, 0.2f * cr);
  const float P1 = __expf(s1r - cr), Q1 = __expf(0.2f * s1r - cr);
  const unsigned long long* brow = bits + (size_t)row * (NN / 64) + (jbase >> 6);
  f32x4 acc[4] = {};
  float wsum = 0.f;
  unsigned long long bw = brow[0];
  for (int jw = 0; jw < 32; ++jw) {
    unsigned long long bwn = brow[jw < 31 ? jw + 1 : 31];
    #pragma unroll
    for (int js = 0; js < 2; ++js) {
      unsigned int m32 = (unsigned int)(bw >> (js * 32));
      const int jl = jw * 64 + js * 32;
      float4 sl = *reinterpret_cast<const float4*>(&s2l[jl + grp * 4]);
      float4 sh = *reinterpret_cast<const float4*>(&s2l[jl + 16 + grp * 4]);
      float4 pl = *reinterpret_cast<const float4*>(&epl[jl + grp * 4]);
      float4 ph = *reinterpret_cast<const float4*>(&epl[jl + 16 + grp * 4]);
      float4 ql = *reinterpret_cast<const float4*>(&enl[jl + grp * 4]);
      float4 qh = *reinterpret_cast<const float4*>(&enl[jl + 16 + grp * 4]);
      unsigned int mg  = m32 >> (grp * 4);
      unsigned int mgh = m32 >> (16 + grp * 4);
      f16x8 af;
      #pragma unroll
      for (int e = 0; e < 4; ++e) {
        float s  = s1r + ((const float*)&sl)[e];
        float v  = s >= 0.f ? P1 * ((const float*)&pl)[e] : Q1 * ((const float*)&ql)[e];
        v = ((mg >> e) & 1u) ? v : 0.f;
        wsum += v; af[e] = (_Float16)v;
        float s2_ = s1r + ((const float*)&sh)[e];
        float v2  = s2_ >= 0.f ? P1 * ((const float*)&ph)[e] : Q1 * ((const float*)&qh)[e];
        v2 = ((mgh >> e) & 1u) ? v2 : 0.f;
        wsum += v2; af[4 + e] = (_Float16)v2;
      }
      const int jbg = jh * 64 + jw * 2 + js;
      #pragma unroll
      for (int n = 0; n < 4; ++n) {
        f16x8 bf = *reinterpret_cast<const f16x8*>(HWF + (size_t)((k * 128 + jbg) * 4 + n) * 512 + lane * 8);
        acc[n] = __builtin_amdgcn_mfma_f32_16x16x32_f16(af, bf, acc[n], 0, 0, 0);
      }
    }
    bw = bwn;
  }
  wsum += __shfl_xor(wsum, 16);
  wsum += __shfl_xor(wsum, 32);
  const size_t pbase = (size_t)jh * KK * NN * DD;
  #pragma unroll
  for (int n = 0; n < 4; ++n)
    #pragma unroll
    for (int q = 0; q < 4; ++q)
      pacc[pbase + ((size_t)k * NN + i0 + w * 16 + grp * 4 + q) * DD + n * 16 + l15] = acc[n][q];
  if (grp == 0) pw[(size_t)jh * KK * NN + k * NN + row] = wsum;
}

// ---------------- K7: merge halves + bias + ELU -----------------------------
__global__ __launch_bounds__(256) void k_merge(const float* __restrict__ pacc,
                                               const float* __restrict__ pw,
                                               const float* __restrict__ bias,
                                               float* __restrict__ out) {
  const int o4 = blockIdx.x * 256 + threadIdx.x;  // 0..524287
  const int i = o4 >> 7, rem = o4 & 127, k = rem >> 4, d4 = rem & 15;
  const size_t half = (size_t)KK * NN * DD;
  const size_t idx = ((size_t)k * NN + i) * DD + d4 * 4;
  float4 a0 = *reinterpret_cast<const float4*>(pacc + idx);
  float4 a1 = *reinterpret_cast<const float4*>(pacc + half + idx);
  float rw = 1.0f / (pw[k * NN + i] + pw[KK * NN + k * NN + i]);
  float4 bv = *reinterpret_cast<const float4*>(bias + k * DD + d4 * 4);
  float4 r;
  r.x = (a0.x + a1.x) * rw + bv.x; r.x = r.x > 0.f ? r.x : expm1f(r.x);
  r.y = (a0.y + a1.y) * rw + bv.y; r.y = r.y > 0.f ? r.y : expm1f(r.y);
  r.z = (a0.z + a1.z) * rw + bv.z; r.z = r.z > 0.f ? r.z : expm1f(r.z);
  r.w = (a0.w + a1.w) * rw + bv.w; r.w = r.w > 0.f ? r.w : expm1f(r.w);
  *reinterpret_cast<float4*>(out + (size_t)o4 * 4) = r;
}

// ---------------------------------------------------------------------------
extern "C" void kernel_launch(void* const* d_in, const int* in_sizes, int n_in,
                              void* d_out, int out_size, void* d_ws, size_t ws_size,
                              hipStream_t stream) {
  const float* H    = (const float*)d_in[0];
  const float* A    = (const float*)d_in[1];
  // d_in[2] = idx = arange(N) -> identity gather, ignored
  const float* Wk   = (const float*)d_in[3];
  const float* attk = (const float*)d_in[4];
  const float* bias = (const float*)d_in[5];
  float* out = (float*)d_out;

  char* base = (char*)d_ws;
  _Float16* HF  = (_Float16*)(base + 0);                      // 4 MB
  _Float16* WF  = (_Float16*)(base + 4194304);                // 512 KB
  _Float16* HWF = (_Float16*)(base + 4718592);                // 4 MB
  unsigned long long* bits = (unsigned long long*)(base + 8912896); // 2 MB
  float* s1p  = (float*)(base + 11010048);                    // 128 KB
  float* s2p  = (float*)(base + 11141120);                    // 128 KB
  float* e2pp = (float*)(base + 11272192);                    // 128 KB
  float* e2np = (float*)(base + 11403264);                    // 128 KB
  float* mxp  = (float*)(base + 11534336);                    // 256 B
  float* pacc = (float*)(base + 11534592);                    // 16 MB
  float* pwp  = (float*)(base + 28311808);                    // 256 KB

  k_bits<<<2048, 256, 0, stream>>>(A, bits);
  k_hf<<<1024, 256, 0, stream>>>(H, HF);
  k_wf<<<128, 256, 0, stream>>>(Wk, WF);
  k_hw<<<dim3(NN / 64, KK), 256, 0, stream>>>(HF, WF, attk, HWF, s1p, s2p, e2pp, e2np);
  k_mx<<<KK, 256, 0, stream>>>(s2p, mxp);
  k_attn<<<dim3(NN / 64, KK, 2), 256, 0, stream>>>(bits, HWF, s1p, s2p, e2pp, e2np, mxp, pacc, pwp);
  k_merge<<<2048, 256, 0, stream>>>(pacc, pwp, bias, out);
}

// Round 4
// 176.244 us; speedup vs baseline: 5.0377x; 1.1220x over previous
//
#include <hip/hip_runtime.h>
#include <hip/hip_fp16.h>
#include <float.h>
#include <math.h>

#define NN 4096
#define FF 512
#define KK 8
#define DD 64

typedef float f32x4 __attribute__((ext_vector_type(4)));
typedef _Float16 h2 __attribute__((ext_vector_type(2)));
typedef _Float16 f16x4 __attribute__((ext_vector_type(4)));
typedef _Float16 f16x8 __attribute__((ext_vector_type(8)));
typedef unsigned int u32;
typedef unsigned long long u64;

__device__ __forceinline__ h2 H2(u32 u) { union { u32 u; h2 h; } x; x.u = u; return x.h; }
__device__ __forceinline__ u32 U32(h2 h) { union { u32 u; h2 h; } x; x.h = h; return x.u; }
// bits (b0,b1) at [sh] of m -> {0 / 0xFFFF low} | {0 / 0xFFFE0000 high} AND-mask
__device__ __forceinline__ u32 pmask(u32 m, int sh) {
  u32 b = (m >> sh) & 3u;
  return ((b * 0x10001u) & 0x20001u) * 0xFFFFu;
}

// ---------------- K1: adjacency -> bitmask ----------------------------------
__global__ __launch_bounds__(256) void k_bits(const float* __restrict__ A,
                                              u64* __restrict__ bits) {
  const int gw = (blockIdx.x * 256 + threadIdx.x) >> 6;
  const int lane = threadIdx.x & 63;
  const int nw = (gridDim.x * 256) >> 6;
  const int totw = NN * NN / 64;
  for (int wd = gw; wd < totw; wd += nw) {
    float a = A[(size_t)wd * 64 + lane];
    u64 m = __ballot(a != 0.0f);
    if (lane == 0) bits[wd] = m;
  }
}

// ---------------- K2: H (fp32) -> HF (A-fragment-major f16) -----------------
__global__ __launch_bounds__(256) void k_hf(const float* __restrict__ H,
                                            _Float16* __restrict__ HF) {
  const int w = threadIdx.x >> 6, lane = threadIdx.x & 63;
  const int tile = blockIdx.x * 4 + w;            // 0..4095
  const int rb = tile >> 4, fb = tile & 15;
  const int l15 = lane & 15, grp = lane >> 4;
  const float* src = H + (size_t)(rb * 16 + l15) * FF + fb * 32 + grp * 4;
  float4 lo = *reinterpret_cast<const float4*>(src);
  float4 hi = *reinterpret_cast<const float4*>(src + 16);
  f16x8 v;
  v[0] = (_Float16)lo.x; v[1] = (_Float16)lo.y; v[2] = (_Float16)lo.z; v[3] = (_Float16)lo.w;
  v[4] = (_Float16)hi.x; v[5] = (_Float16)hi.y; v[6] = (_Float16)hi.z; v[7] = (_Float16)hi.w;
  *reinterpret_cast<f16x8*>(HF + (size_t)tile * 512 + lane * 8) = v;
}

// ---------------- K3: W -> WF (B-fragment-major f16) ------------------------
__global__ __launch_bounds__(256) void k_wf(const float* __restrict__ Wk,
                                            _Float16* __restrict__ WF) {
  const int g = blockIdx.x * 256 + threadIdx.x;
  const int frag = g >> 6, lane = g & 63;
  const int k = frag >> 6, fb = (frag >> 2) & 15, db = frag & 3;
  const int l15 = lane & 15, grp = lane >> 4;
  f16x8 v;
  #pragma unroll
  for (int e = 0; e < 8; ++e) {
    int f = fb * 32 + grp * 4 + (e & 3) + 16 * (e >> 2);
    int d = db * 16 + l15;
    v[e] = (_Float16)Wk[((size_t)k * FF + f) * DD + d];
  }
  *reinterpret_cast<f16x8*>(WF + (size_t)frag * 512 + lane * 8) = v;
}

// ---------------- K4: HW = H@W (MFMA, LDS B-stage) + s1/s2 + HWF ------------
__global__ __launch_bounds__(256) void k_hw(const _Float16* __restrict__ HF,
                                            const _Float16* __restrict__ WF,
                                            const float* __restrict__ attk,
                                            _Float16* __restrict__ HWF,
                                            float* __restrict__ s1,
                                            float* __restrict__ s2) {
  __shared__ __align__(16) _Float16 Bs[64 * 512];   // 64 KB: this head's W-frags
  const int w = threadIdx.x >> 6, lane = threadIdx.x & 63;
  const int k = blockIdx.y;
  const int rb = blockIdx.x * 4 + w;                // 16-row block
  const int l15 = lane & 15, grp = lane >> 4;
  // stage all 64 B-frags (16 fb x 4 db) cooperatively
  const _Float16* wfk = WF + (size_t)k * 64 * 512;
  #pragma unroll
  for (int c = 0; c < 16; ++c) {
    int chunk = c * 4 + w;
    *reinterpret_cast<f16x8*>(&Bs[chunk * 512 + lane * 8]) =
        *reinterpret_cast<const f16x8*>(wfk + (size_t)chunk * 512 + lane * 8);
  }
  __syncthreads();
  f32x4 acc[4] = {};
  for (int fb = 0; fb < 16; ++fb) {
    f16x8 a = *reinterpret_cast<const f16x8*>(HF + (size_t)(rb * 16 + fb) * 512 + lane * 8);
    #pragma unroll
    for (int n = 0; n < 4; ++n) {
      f16x8 b = *reinterpret_cast<const f16x8*>(&Bs[(fb * 4 + n) * 512 + lane * 8]);
      acc[n] = __builtin_amdgcn_mfma_f32_16x16x32_f16(a, b, acc[n], 0, 0, 0);
    }
  }
  // HWF in k_attn B-frag layout: frag=(k*128+jb)*4+db, this wave fills half (rb&1)
  const int jb = rb >> 1;
  const int half = rb & 1;
  #pragma unroll
  for (int db = 0; db < 4; ++db) {
    f16x4 v;
    #pragma unroll
    for (int q = 0; q < 4; ++q) v[q] = (_Float16)acc[db][q];
    *reinterpret_cast<f16x4*>(HWF + (size_t)((k * 128 + jb) * 4 + db) * 512 + lane * 8 + half * 4) = v;
  }
  // s1/s2 reductions
  float a1v[4], a2v[4];
  #pragma unroll
  for (int n = 0; n < 4; ++n) {
    a1v[n] = attk[k * 2 * DD + n * 16 + l15];
    a2v[n] = attk[k * 2 * DD + DD + n * 16 + l15];
  }
  #pragma unroll
  for (int q = 0; q < 4; ++q) {
    float p1 = 0.f, p2 = 0.f;
    #pragma unroll
    for (int n = 0; n < 4; ++n) { p1 += acc[n][q] * a1v[n]; p2 += acc[n][q] * a2v[n]; }
    #pragma unroll
    for (int off = 8; off; off >>= 1) { p1 += __shfl_xor(p1, off); p2 += __shfl_xor(p2, off); }
    if (l15 == 0) {
      int row = rb * 16 + grp * 4 + q;
      s1[k * NN + row] = p1;
      s2[k * NN + row] = p2;
    }
  }
}

// ---------------- K5: maxs2[k] ----------------------------------------------
__global__ __launch_bounds__(256) void k_mx(const float* __restrict__ s2,
                                            float* __restrict__ mx) {
  const int k = blockIdx.x, tid = threadIdx.x;
  float m = -FLT_MAX;
  for (int j = tid; j < NN; j += 256) m = fmaxf(m, s2[k * NN + j]);
  #pragma unroll
  for (int o = 32; o; o >>= 1) m = fmaxf(m, __shfl_xor(m, o));
  __shared__ float sm[4];
  if ((tid & 63) == 0) sm[tid >> 6] = m;
  __syncthreads();
  if (tid == 0) mx[k] = fmaxf(fmaxf(sm[0], sm[1]), fmaxf(sm[2], sm[3]));
}

// ---------------- K6: attn-PV, packed f16, quad-row waves -------------------
// w_ij = A_ij * max(P1_i*ep[j], Q1_i*en[j]);  ep=e^{s2-mx}, en=e^{0.2(s2-mx)}
__global__ __launch_bounds__(256, 2) void k_attn(
    const u64* __restrict__ bits, const _Float16* __restrict__ HWF,
    const float* __restrict__ s1, const float* __restrict__ s2,
    const float* __restrict__ mx,
    _Float16* __restrict__ pacc, float* __restrict__ pw) {
  __shared__ __align__(16) _Float16 epl[1024];
  __shared__ __align__(16) _Float16 enl[1024];
  const int k = blockIdx.y, jh = blockIdx.z;
  const int i0 = blockIdx.x * 256;
  const int tid = threadIdx.x;
  const int w = tid >> 6, lane = tid & 63, l15 = lane & 15, grp = lane >> 4;
  const int jbase = jh * 1024;
  const float mxk = mx[k];
  {
    float4 sv = *reinterpret_cast<const float4*>(&s2[k * NN + jbase + tid * 4]);
    f16x4 e4, n4;
    e4[0] = (_Float16)__expf(sv.x - mxk); e4[1] = (_Float16)__expf(sv.y - mxk);
    e4[2] = (_Float16)__expf(sv.z - mxk); e4[3] = (_Float16)__expf(sv.w - mxk);
    n4[0] = (_Float16)__expf(0.2f * (sv.x - mxk)); n4[1] = (_Float16)__expf(0.2f * (sv.y - mxk));
    n4[2] = (_Float16)__expf(0.2f * (sv.z - mxk)); n4[3] = (_Float16)__expf(0.2f * (sv.w - mxk));
    *reinterpret_cast<f16x4*>(&epl[tid * 4]) = e4;
    *reinterpret_cast<f16x4*>(&enl[tid * 4]) = n4;
  }
  __syncthreads();
  h2 P1h[4], Q1h[4];
  const u64* browp[4];
  #pragma unroll
  for (int s = 0; s < 4; ++s) {
    int row = i0 + w * 64 + s * 16 + l15;
    float s1r = s1[k * NN + row];
    float t = s1r + mxk;
    float cr = fmaxf(t, 0.2f * t);
    _Float16 p = (_Float16)__expf(t - cr);
    _Float16 q = (_Float16)__expf(0.2f * t - cr);
    P1h[s] = h2{p, p}; Q1h[s] = h2{q, q};
    browp[s] = bits + (size_t)row * (NN / 64) + (jbase >> 6);
  }
  const int g4 = grp * 4;
  const _Float16* hwb = HWF + ((size_t)(k * 128 + jh * 32) * 4) * 512 + lane * 8;
  const h2 ones = h2{(_Float16)1.0f, (_Float16)1.0f};
  f32x4 acc[4][4] = {};
  float wsum[4] = {};
  u64 bw[4];
  #pragma unroll
  for (int s = 0; s < 4; ++s) bw[s] = browp[s][0];
  for (int jw = 0; jw < 16; ++jw) {
    u64 nbw[4];
    const int nx = jw < 15 ? jw + 1 : 15;
    #pragma unroll
    for (int s = 0; s < 4; ++s) nbw[s] = browp[s][nx];
    #pragma unroll
    for (int js = 0; js < 2; ++js) {
      const int jl = jw * 64 + js * 32;
      f16x8 bf0 = *reinterpret_cast<const f16x8*>(hwb + ((jw * 2 + js) * 4 + 0) * 512);
      f16x8 bf1 = *reinterpret_cast<const f16x8*>(hwb + ((jw * 2 + js) * 4 + 1) * 512);
      f16x8 bf2 = *reinterpret_cast<const f16x8*>(hwb + ((jw * 2 + js) * 4 + 2) * 512);
      f16x8 bf3 = *reinterpret_cast<const f16x8*>(hwb + ((jw * 2 + js) * 4 + 3) * 512);
      f16x4 elo = *reinterpret_cast<const f16x4*>(&epl[jl + g4]);
      f16x4 ehi = *reinterpret_cast<const f16x4*>(&epl[jl + 16 + g4]);
      f16x4 nlo = *reinterpret_cast<const f16x4*>(&enl[jl + g4]);
      f16x4 nhi = *reinterpret_cast<const f16x4*>(&enl[jl + 16 + g4]);
      const u32 e01 = ((const u32*)&elo)[0], e23 = ((const u32*)&elo)[1];
      const u32 e45 = ((const u32*)&ehi)[0], e67 = ((const u32*)&ehi)[1];
      const u32 n01 = ((const u32*)&nlo)[0], n23 = ((const u32*)&nlo)[1];
      const u32 n45 = ((const u32*)&nhi)[0], n67 = ((const u32*)&nhi)[1];
      #pragma unroll
      for (int s = 0; s < 4; ++s) {
        const u32 m32 = (u32)(bw[s] >> (js * 32));
        u32 p0 = U32(__builtin_elementwise_max(P1h[s] * H2(e01), Q1h[s] * H2(n01))) & pmask(m32, g4);
        u32 p1 = U32(__builtin_elementwise_max(P1h[s] * H2(e23), Q1h[s] * H2(n23))) & pmask(m32, g4 + 2);
        u32 p2 = U32(__builtin_elementwise_max(P1h[s] * H2(e45), Q1h[s] * H2(n45))) & pmask(m32, g4 + 16);
        u32 p3 = U32(__builtin_elementwise_max(P1h[s] * H2(e67), Q1h[s] * H2(n67))) & pmask(m32, g4 + 18);
        wsum[s] = __builtin_amdgcn_fdot2(H2(p0), ones, wsum[s], false);
        wsum[s] = __builtin_amdgcn_fdot2(H2(p1), ones, wsum[s], false);
        wsum[s] = __builtin_amdgcn_fdot2(H2(p2), ones, wsum[s], false);
        wsum[s] = __builtin_amdgcn_fdot2(H2(p3), ones, wsum[s], false);
        union { u32 u[4]; f16x8 v; } af;
        af.u[0] = p0; af.u[1] = p1; af.u[2] = p2; af.u[3] = p3;
        acc[s][0] = __builtin_amdgcn_mfma_f32_16x16x32_f16(af.v, bf0, acc[s][0], 0, 0, 0);
        acc[s][1] = __builtin_amdgcn_mfma_f32_16x16x32_f16(af.v, bf1, acc[s][1], 0, 0, 0);
        acc[s][2] = __builtin_amdgcn_mfma_f32_16x16x32_f16(af.v, bf2, acc[s][2], 0, 0, 0);
        acc[s][3] = __builtin_amdgcn_mfma_f32_16x16x32_f16(af.v, bf3, acc[s][3], 0, 0, 0);
      }
    }
    #pragma unroll
    for (int s = 0; s < 4; ++s) bw[s] = nbw[s];
  }
  const size_t ob = (size_t)(jh * KK + k) * NN;
  #pragma unroll
  for (int s = 0; s < 4; ++s) {
    float ws = wsum[s];
    ws += __shfl_xor(ws, 16);
    ws += __shfl_xor(ws, 32);
    #pragma unroll
    for (int n = 0; n < 4; ++n)
      #pragma unroll
      for (int q = 0; q < 4; ++q) {
        int row = i0 + w * 64 + s * 16 + grp * 4 + q;
        pacc[(ob + row) * DD + n * 16 + l15] = (_Float16)acc[s][n][q];
      }
    if (grp == 0) {
      int row = i0 + w * 64 + s * 16 + l15;
      pw[ob + row] = ws;
    }
  }
}

// ---------------- K7: merge 4 j-slices + bias + ELU -------------------------
__global__ __launch_bounds__(256) void k_merge(const _Float16* __restrict__ pacc,
                                               const float* __restrict__ pw,
                                               const float* __restrict__ bias,
                                               float* __restrict__ out) {
  const int o4 = blockIdx.x * 256 + threadIdx.x;  // 0..524287
  const int i = o4 >> 7, rem = o4 & 127, k = rem >> 4, d4 = rem & 15;
  const size_t idx = ((size_t)k * NN + i) * DD + d4 * 4;
  float4 a = {0.f, 0.f, 0.f, 0.f};
  float wsum = 0.f;
  #pragma unroll
  for (int s = 0; s < 4; ++s) {
    f16x4 v = *reinterpret_cast<const f16x4*>(&pacc[(size_t)s * (KK * NN * DD) + idx]);
    a.x += (float)v[0]; a.y += (float)v[1]; a.z += (float)v[2]; a.w += (float)v[3];
    wsum += pw[(size_t)s * (KK * NN) + k * NN + i];
  }
  float rw = 1.0f / wsum;
  float4 bv = *reinterpret_cast<const float4*>(bias + k * DD + d4 * 4);
  float4 r;
  r.x = a.x * rw + bv.x; r.x = r.x > 0.f ? r.x : expm1f(r.x);
  r.y = a.y * rw + bv.y; r.y = r.y > 0.f ? r.y : expm1f(r.y);
  r.z = a.z * rw + bv.z; r.z = r.z > 0.f ? r.z : expm1f(r.z);
  r.w = a.w * rw + bv.w; r.w = r.w > 0.f ? r.w : expm1f(r.w);
  *reinterpret_cast<float4*>(out + (size_t)o4 * 4) = r;
}

// ---------------------------------------------------------------------------
extern "C" void kernel_launch(void* const* d_in, const int* in_sizes, int n_in,
                              void* d_out, int out_size, void* d_ws, size_t ws_size,
                              hipStream_t stream) {
  const float* H    = (const float*)d_in[0];
  const float* A    = (const float*)d_in[1];
  // d_in[2] = idx = arange(N) -> identity gather, ignored
  const float* Wk   = (const float*)d_in[3];
  const float* attk = (const float*)d_in[4];
  const float* bias = (const float*)d_in[5];
  float* out = (float*)d_out;

  char* base = (char*)d_ws;
  _Float16* HF  = (_Float16*)(base + 0);                       // 4 MB
  _Float16* WF  = (_Float16*)(base + 4194304);                 // 512 KB
  _Float16* HWF = (_Float16*)(base + 4718592);                 // 4 MB
  u64* bits     = (u64*)(base + 8912896);                      // 2 MB
  float* s1p    = (float*)(base + 11010048);                   // 128 KB
  float* s2p    = (float*)(base + 11141120);                   // 128 KB
  float* mxp    = (float*)(base + 11272192);                   // 4 KB
  _Float16* pacc = (_Float16*)(base + 11276288);               // 16 MB
  float* pwp    = (float*)(base + 28053504);                   // 512 KB

  k_bits<<<2048, 256, 0, stream>>>(A, bits);
  k_hf<<<1024, 256, 0, stream>>>(H, HF);
  k_wf<<<128, 256, 0, stream>>>(Wk, WF);
  k_hw<<<dim3(NN / 64, KK), 256, 0, stream>>>(HF, WF, attk, HWF, s1p, s2p);
  k_mx<<<KK, 256, 0, stream>>>(s2p, mxp);
  k_attn<<<dim3(NN / 256, KK, 4), 256, 0, stream>>>(bits, HWF, s1p, s2p, mxp, pacc, pwp);
  k_merge<<<2048, 256, 0, stream>>>(pacc, pwp, bias, out);
}